// Round 10
// baseline (297.964 us; speedup 1.0000x reference)
//
#include <hip/hip_runtime.h>

#define BB 64
#define PP 256
#define NN 1000
#define NP 1024   // padded KV rows (power of 2, zero-filled beyond NN)
#define EE 128
#define HH 8
#define DD 16
// H*D = 128

typedef __fp16 v4h __attribute__((ext_vector_type(4)));
typedef float v4f __attribute__((ext_vector_type(4)));

// Shared MFMA GEMM convention (validated in k3/k5 since R2):
//   af = X[m = lane&15][k = 4*(lane>>4)+j]      (v4h)
//   bf = W^T[n = lane&15][k = 4*(lane>>4)+j]    (v4h, from LDS)
//   D  = mfma(af, bf, acc):  acc[r] = C[m = 4*(lane>>4)+r][n = lane&15]

// ---------------------------------------------------------------------------
// k1: Q projection, MFMA.  Qh = 0.25 * (concat(ln, attr) @ Wq), fp16 out.
// ---------------------------------------------------------------------------
__global__ __launch_bounds__(256) void k1_qproj(const float* __restrict__ ln,
                                                const float* __restrict__ attr,
                                                const float* __restrict__ Wq,
                                                __fp16* __restrict__ Qh) {
    __shared__ __fp16 wt[128 * 132];   // Wq^T[n][k], first 128 k-rows
    __shared__ float attrs[64];
    const int tid = threadIdx.x;
    const int row0 = blockIdx.x * 64;   // 256 blocks
    for (int i = tid; i < 128 * 128; i += 256) {
        int k = i >> 7, n = i & 127;
        wt[n * 132 + k] = (__fp16)Wq[i];
    }
    if (tid < 64) attrs[tid] = attr[row0 + tid];
    __syncthreads();

    const int wid = tid >> 6, lane = tid & 63;
    const int lp = lane & 15, lg = lane >> 4;
    const int rb = row0 + wid * 16;

    const float* arow = ln + (size_t)(rb + lp) * 128;
    v4f acc[8];
#pragma unroll
    for (int cf = 0; cf < 8; cf++) acc[cf] = (v4f){0.f, 0.f, 0.f, 0.f};

#pragma unroll
    for (int k0 = 0; k0 < 8; k0++) {
        float4 av = *(const float4*)&arow[k0 * 16 + 4 * lg];
        v4h af;
        af[0] = (__fp16)av.x; af[1] = (__fp16)av.y;
        af[2] = (__fp16)av.z; af[3] = (__fp16)av.w;
#pragma unroll
        for (int cf = 0; cf < 8; cf++) {
            v4h bf = *(const v4h*)&wt[(cf * 16 + lp) * 132 + k0 * 16 + 4 * lg];
            acc[cf] = __builtin_amdgcn_mfma_f32_16x16x16f16(af, bf, acc[cf], 0, 0, 0);
        }
    }

#pragma unroll
    for (int cf = 0; cf < 8; cf++) {
        const int col = cf * 16 + lp;
        const float w128 = Wq[128 * 128 + col];
#pragma unroll
        for (int r = 0; r < 4; r++) {
            const int rl = wid * 16 + 4 * lg + r;
            float v = (acc[cf][r] + attrs[rl] * w128) * 0.25f;
            Qh[(size_t)(row0 + rl) * 128 + col] = (__fp16)v;
        }
    }
}

// ---------------------------------------------------------------------------
// k2: K/V projection, MFMA.  blockIdx.z: 0 -> Kf, 1 -> Vt.  Both stored as
// 16x16 tiles with ROTATED granule order so a wave's fragment read of tile s
// (lane offset 64*lg + 4*lp) is 512 B contiguous — dense from global:
//   Kf tile: half = (d>>2)*64 + n*4 + (d&3)
//   Vt tile: half = (n>>2)*64 + d*4 + (n&3)
// ---------------------------------------------------------------------------
__global__ __launch_bounds__(256) void k2_kv(const float* __restrict__ nodes,
                                             const float* __restrict__ Wk,
                                             const float* __restrict__ Wv,
                                             __fp16* __restrict__ Kf,
                                             __fp16* __restrict__ Vt) {
    __shared__ __fp16 wt[128 * 132];   // W^T[n][k]
    const int tid = threadIdx.x;
    const int b = blockIdx.y;
    const int kv = blockIdx.z;
    const float* W = (kv == 0) ? Wk : Wv;
    for (int i = tid; i < 128 * 128; i += 256) {
        int k = i >> 7, n = i & 127;
        wt[n * 132 + k] = (__fp16)W[i];
    }
    __syncthreads();

    const int wid = tid >> 6, lane = tid & 63;
    const int lp = lane & 15, lg = lane >> 4;
    const int nb = blockIdx.x * 64 + wid * 16;   // 16 x-blocks -> rows 0..1023

    int nr = nb + lp;
    if (nr >= NN) nr = NN - 1;                   // clamp; garbage zeroed on store
    const float* arow = nodes + (size_t)(b * NN + nr) * 128;

    v4f acc[8];
#pragma unroll
    for (int cf = 0; cf < 8; cf++) acc[cf] = (v4f){0.f, 0.f, 0.f, 0.f};

#pragma unroll
    for (int k0 = 0; k0 < 8; k0++) {
        float4 av = *(const float4*)&arow[k0 * 16 + 4 * lg];
        v4h af;
        af[0] = (__fp16)av.x; af[1] = (__fp16)av.y;
        af[2] = (__fp16)av.z; af[3] = (__fp16)av.w;
#pragma unroll
        for (int cf = 0; cf < 8; cf++) {
            v4h bf = *(const v4h*)&wt[(cf * 16 + lp) * 132 + k0 * 16 + 4 * lg];
            acc[cf] = __builtin_amdgcn_mfma_f32_16x16x16f16(af, bf, acc[cf], 0, 0, 0);
        }
    }

    if (kv == 0) {
        // element (n = nb+4lg+r, d = lp) -> half:
        //   (nb>>4)*256 + (lp>>2)*64 + (4lg+r)*4 + (lp&3)
#pragma unroll
        for (int cf = 0; cf < 8; cf++) {
            const size_t base = ((size_t)(b * HH + cf) << 14) +
                                (size_t)(nb >> 4) * 256 + (lp >> 2) * 64 + (lp & 3);
#pragma unroll
            for (int r = 0; r < 4; r++) {
                const int n = nb + 4 * lg + r;
                Kf[base + (4 * lg + r) * 4] = (n < NN) ? (__fp16)acc[cf][r] : (__fp16)0.f;
            }
        }
    } else {
        // v4h (n-quad lg, d = lp) -> half base: (nb>>4)*256 + lg*64 + lp*4
#pragma unroll
        for (int cf = 0; cf < 8; cf++) {
            v4h pk;
#pragma unroll
            for (int r = 0; r < 4; r++) {
                const int n = nb + 4 * lg + r;
                pk[r] = (n < NN) ? (__fp16)acc[cf][r] : (__fp16)0.f;
            }
            *(v4h*)&Vt[((size_t)(b * HH + cf) << 14) + (size_t)(nb >> 4) * 256 +
                       lg * 64 + lp * 4] = pk;
        }
    }
}

// ---------------------------------------------------------------------------
// k3: MFMA attention.  R14: ZERO LDS, ZERO barriers.  Rotated tile layout
// makes each wave's fragment load 512 B dense from global (8 lines), so
// fragments are loaded directly into registers; the block's 4 waves read
// identical tiles -> L1 hits.  No barrier -> no vmcnt(0) drains -> compiler
// pipelines loads across iterations with counted waitcnt.
// ---------------------------------------------------------------------------
__global__ __launch_bounds__(256) void k3_attn(const __fp16* __restrict__ Qh,
                                               const __fp16* __restrict__ Kf,
                                               const __fp16* __restrict__ Vt,
                                               const float* __restrict__ mask,
                                               __fp16* __restrict__ Aout) {
    const int tid = threadIdx.x;
    const int bid = blockIdx.x;            // 1024
    const int b = bid & 63;                // bid&7 = b&7 -> XCD locality on b
    const int rest = bid >> 6;             // 0..15
    const int hg = rest & 3, pt = rest >> 2;
    const int h0 = hg * 2;
    const int p0 = pt * 64;

    const int wid = tid >> 6, lane = tid & 63;
    const int lp = lane & 15, lg = lane >> 4;
    const int pw = p0 + wid * 16;

    const int foff = 64 * lg + 4 * lp;     // rotated-layout fragment offset
    const __fp16* kp0 = Kf + ((size_t)(b * HH + h0) << 14) + foff;
    const __fp16* kp1 = kp0 + (1 << 14);
    const __fp16* vp0 = Vt + ((size_t)(b * HH + h0) << 14) + foff;
    const __fp16* vp1 = vp0 + (1 << 14);

    v4h qf[2];
    {
        const __fp16* qrow = Qh + (size_t)(b * PP + pw + lp) * 128 + h0 * 16 + 4 * lg;
        qf[0] = *(const v4h*)&qrow[0];
        qf[1] = *(const v4h*)&qrow[16];
    }

    const float* mrow = mask + (size_t)(b * PP + pw + lp) * NN;

    v4f acc[2];
    float lsum[2];
    acc[0] = (v4f){0.f, 0.f, 0.f, 0.f};
    acc[1] = (v4f){0.f, 0.f, 0.f, 0.f};
    lsum[0] = 0.f; lsum[1] = 0.f;
    const v4f zero4 = {0.f, 0.f, 0.f, 0.f};

#pragma unroll 2
    for (int s = 0; s < 62; s++) {
        v4h kf0 = *(const v4h*)&kp0[s * 256];
        v4h kf1 = *(const v4h*)&kp1[s * 256];
        v4h vf0 = *(const v4h*)&vp0[s * 256];
        v4h vf1 = *(const v4h*)&vp1[s * 256];
        float4 m = *(const float4*)&mrow[s * 16 + 4 * lg];
        {
            v4f sc = __builtin_amdgcn_mfma_f32_16x16x16f16(kf0, qf[0], zero4, 0, 0, 0);
            float w0 = __expf(sc[0] + m.x);
            float w1 = __expf(sc[1] + m.y);
            float w2 = __expf(sc[2] + m.z);
            float w3 = __expf(sc[3] + m.w);
            lsum[0] += (w0 + w1) + (w2 + w3);
            v4h wf;
            wf[0] = (__fp16)w0; wf[1] = (__fp16)w1; wf[2] = (__fp16)w2; wf[3] = (__fp16)w3;
            acc[0] = __builtin_amdgcn_mfma_f32_16x16x16f16(wf, vf0, acc[0], 0, 0, 0);
        }
        {
            v4f sc = __builtin_amdgcn_mfma_f32_16x16x16f16(kf1, qf[1], zero4, 0, 0, 0);
            float w0 = __expf(sc[0] + m.x);
            float w1 = __expf(sc[1] + m.y);
            float w2 = __expf(sc[2] + m.z);
            float w3 = __expf(sc[3] + m.w);
            lsum[1] += (w0 + w1) + (w2 + w3);
            v4h wf;
            wf[0] = (__fp16)w0; wf[1] = (__fp16)w1; wf[2] = (__fp16)w2; wf[3] = (__fp16)w3;
            acc[1] = __builtin_amdgcn_mfma_f32_16x16x16f16(wf, vf1, acc[1], 0, 0, 0);
        }
    }

    {   // tail step s=62: n = 992 + 4*lg + r, bounds-guarded
        const int s = 62;
        v4h kf0 = *(const v4h*)&kp0[s * 256];
        v4h kf1 = *(const v4h*)&kp1[s * 256];
        v4h vf0 = *(const v4h*)&vp0[s * 256];
        v4h vf1 = *(const v4h*)&vp1[s * 256];
        int nc = 992 + 4 * lg; if (nc > 996) nc = 996;
        float4 m = *(const float4*)&mrow[nc];
        const bool c0 = (992 + 4 * lg + 0 < NN), c1 = (992 + 4 * lg + 1 < NN);
        const bool c2 = (992 + 4 * lg + 2 < NN), c3 = (992 + 4 * lg + 3 < NN);
        {
            v4f sc = __builtin_amdgcn_mfma_f32_16x16x16f16(kf0, qf[0], zero4, 0, 0, 0);
            float w0 = c0 ? __expf(sc[0] + m.x) : 0.f;
            float w1 = c1 ? __expf(sc[1] + m.y) : 0.f;
            float w2 = c2 ? __expf(sc[2] + m.z) : 0.f;
            float w3 = c3 ? __expf(sc[3] + m.w) : 0.f;
            lsum[0] += (w0 + w1) + (w2 + w3);
            v4h wf;
            wf[0] = (__fp16)w0; wf[1] = (__fp16)w1; wf[2] = (__fp16)w2; wf[3] = (__fp16)w3;
            acc[0] = __builtin_amdgcn_mfma_f32_16x16x16f16(wf, vf0, acc[0], 0, 0, 0);
        }
        {
            v4f sc = __builtin_amdgcn_mfma_f32_16x16x16f16(kf1, qf[1], zero4, 0, 0, 0);
            float w0 = c0 ? __expf(sc[0] + m.x) : 0.f;
            float w1 = c1 ? __expf(sc[1] + m.y) : 0.f;
            float w2 = c2 ? __expf(sc[2] + m.z) : 0.f;
            float w3 = c3 ? __expf(sc[3] + m.w) : 0.f;
            lsum[1] += (w0 + w1) + (w2 + w3);
            v4h wf;
            wf[0] = (__fp16)w0; wf[1] = (__fp16)w1; wf[2] = (__fp16)w2; wf[3] = (__fp16)w3;
            acc[1] = __builtin_amdgcn_mfma_f32_16x16x16f16(wf, vf1, acc[1], 0, 0, 0);
        }
    }

#pragma unroll
    for (int j = 0; j < 2; j++) {
        float l = lsum[j];
        l += __shfl_xor(l, 16);
        l += __shfl_xor(l, 32);
#pragma unroll
        for (int r = 0; r < 4; r++) {
            float denom = __shfl(l, 4 * lg + r);
            float inv = 1.f / denom;
            Aout[(size_t)(b * PP + pw + 4 * lg + r) * 128 + (h0 + j) * 16 + lp] =
                (__fp16)(acc[j][r] * inv);
        }
    }
}

// ---------------------------------------------------------------------------
// k4: mh MFMA.  Ain fp16 (values identical — fp16 rounding moved to k3 store).
// ---------------------------------------------------------------------------
__global__ __launch_bounds__(256) void k4_mh(const __fp16* __restrict__ Ain,
                                             const float* __restrict__ Wo,
                                             const float* __restrict__ bo,
                                             __fp16* __restrict__ Mh) {
    __shared__ __fp16 wt[128 * 132];   // Wo^T[n][k]
    const int tid = threadIdx.x;
    const int row0 = blockIdx.x * 64;
    for (int i = tid; i < 128 * 128; i += 256) {
        int k = i >> 7, n = i & 127;
        wt[n * 132 + k] = (__fp16)Wo[i];
    }
    __syncthreads();

    const int wid = tid >> 6, lane = tid & 63;
    const int lp = lane & 15, lg = lane >> 4;
    const int rb = row0 + wid * 16;

    const __fp16* arow = Ain + (size_t)(rb + lp) * 128;
    v4f acc[8];
#pragma unroll
    for (int cf = 0; cf < 8; cf++) acc[cf] = (v4f){0.f, 0.f, 0.f, 0.f};

#pragma unroll
    for (int k0 = 0; k0 < 8; k0++) {
        v4h af = *(const v4h*)&arow[k0 * 16 + 4 * lg];
#pragma unroll
        for (int cf = 0; cf < 8; cf++) {
            v4h bf = *(const v4h*)&wt[(cf * 16 + lp) * 132 + k0 * 16 + 4 * lg];
            acc[cf] = __builtin_amdgcn_mfma_f32_16x16x16f16(af, bf, acc[cf], 0, 0, 0);
        }
    }

    const float scale = 0.08838834764831845f;   // 1/sqrt(128)
#pragma unroll
    for (int cf = 0; cf < 8; cf++) {
        const int col = cf * 16 + lp;
        const float bb = bo[col];
#pragma unroll
        for (int r = 0; r < 4; r++) {
            const int rl = wid * 16 + 4 * lg + r;
            Mh[(size_t)(row0 + rl) * 128 + col] = (__fp16)((acc[cf][r] + bb) * scale);
        }
    }
}

// ---------------------------------------------------------------------------
// k5: final scoring + tanh-clip softmax.  R11 structure (512 threads,
// 32 p-rows/block, nodes reuse x2, fp32 register double-buffer).
// ---------------------------------------------------------------------------
__device__ __forceinline__ void k5_pref(int s, int wid, int lp, int lg,
                                        const float* __restrict__ nbase,
                                        float4 (&nb)[8]) {
    int nr = s * 128 + wid * 16 + lp;
    if (nr >= NN) nr = NN - 1;
    const float* a = nbase + (size_t)nr * 128 + 4 * lg;
#pragma unroll
    for (int ec = 0; ec < 8; ec++) nb[ec] = *(const float4*)&a[ec * 16];
}

__device__ __forceinline__ void k5_comp(int s, int wid, int lp, int lg,
                                        const v4h (&bf0)[8], const v4h (&bf1)[8],
                                        const float4 (&nb)[8],
                                        const float* __restrict__ mk0,
                                        const float* __restrict__ mk1,
                                        float& ls0, float& ls1,
                                        __fp16* __restrict__ probs) {
    const v4f zero4 = {0.f, 0.f, 0.f, 0.f};
    int mc = s * 128 + wid * 16 + 4 * lg;
    if (mc > 996) mc = 996;
    float4 m0 = *(const float4*)&mk0[mc];
    float4 m1 = *(const float4*)&mk1[mc];
    v4f a0 = zero4, a1 = zero4;
#pragma unroll
    for (int ec = 0; ec < 8; ec++) {
        float4 av = nb[ec];
        v4h af;
        af[0] = (__fp16)av.x; af[1] = (__fp16)av.y;
        af[2] = (__fp16)av.z; af[3] = (__fp16)av.w;
        a0 = __builtin_amdgcn_mfma_f32_16x16x16f16(af, bf0[ec], a0, 0, 0, 0);
        a1 = __builtin_amdgcn_mfma_f32_16x16x16f16(af, bf1[ec], a1, 0, 0, 0);
    }
    const int nt = s * 128 + wid * 16;
    const int nb4 = nt + 4 * lg;
#pragma unroll
    for (int t = 0; t < 2; t++) {
        const v4f ac = t ? a1 : a0;
        const float4 m = t ? m1 : m0;
        v4h wf;
        float ws = 0.f;
        if (nt + 15 < NN) {
            float e0 = __expf(2.f * ac[0]);
            float e1 = __expf(2.f * ac[1]);
            float e2 = __expf(2.f * ac[2]);
            float e3 = __expf(2.f * ac[3]);
            float w0 = __expf(fmaf(-20.f, __builtin_amdgcn_rcpf(e0 + 1.f), m.x));
            float w1 = __expf(fmaf(-20.f, __builtin_amdgcn_rcpf(e1 + 1.f), m.y));
            float w2 = __expf(fmaf(-20.f, __builtin_amdgcn_rcpf(e2 + 1.f), m.z));
            float w3 = __expf(fmaf(-20.f, __builtin_amdgcn_rcpf(e3 + 1.f), m.w));
            ws = (w0 + w1) + (w2 + w3);
            wf[0] = (__fp16)w0; wf[1] = (__fp16)w1; wf[2] = (__fp16)w2; wf[3] = (__fp16)w3;
        } else {
            float w0 = 0.f, w1 = 0.f, w2 = 0.f, w3 = 0.f;
            if (nb4 + 0 < NN) {
                float e = __expf(2.f * ac[0]);
                w0 = __expf(fmaf(-20.f, __builtin_amdgcn_rcpf(e + 1.f), m.x));
            }
            if (nb4 + 1 < NN) {
                float e = __expf(2.f * ac[1]);
                w1 = __expf(fmaf(-20.f, __builtin_amdgcn_rcpf(e + 1.f), m.y));
            }
            if (nb4 + 2 < NN) {
                float e = __expf(2.f * ac[2]);
                w2 = __expf(fmaf(-20.f, __builtin_amdgcn_rcpf(e + 1.f), m.z));
            }
            if (nb4 + 3 < NN) {
                float e = __expf(2.f * ac[3]);
                w3 = __expf(fmaf(-20.f, __builtin_amdgcn_rcpf(e + 1.f), m.w));
            }
            ws = (w0 + w1) + (w2 + w3);
            wf[0] = (__fp16)w0; wf[1] = (__fp16)w1; wf[2] = (__fp16)w2; wf[3] = (__fp16)w3;
        }
        if (t) ls1 += ws; else ls0 += ws;
        *(v4h*)&probs[(t * 16 + lp) * 1028 + nb4] = wf;
    }
}

__global__ __launch_bounds__(512, 4) void k5_final(const float* __restrict__ nodes,
                                                   const __fp16* __restrict__ Mh,
                                                   const float* __restrict__ mask,
                                                   float* __restrict__ out) {
    __shared__ __fp16 probs[32 * 1028];   // 65,792 B
    __shared__ float rowsum[32];
    __shared__ float rowinv[32];
    const int tid = threadIdx.x;
    const int bid = blockIdx.x;          // 512 = 64 b x 8 pt; b&7 = bid&7 (XCD)
    const int xcd = bid & 7;
    const int pt = (bid >> 3) & 7;
    const int b = ((bid >> 6) << 3) | xcd;
    const int p0 = pt * 32;

    if (tid < 32) rowsum[tid] = 0.f;

    const int wid = tid >> 6, lane = tid & 63;
    const int lp = lane & 15, lg = lane >> 4;

    v4h bf0[8], bf1[8];
    {
        const __fp16* mh0 = Mh + (size_t)(b * PP + p0 + lp) * 128;
        const __fp16* mh1 = mh0 + (size_t)16 * 128;
#pragma unroll
        for (int ec = 0; ec < 8; ec++) {
            bf0[ec] = *(const v4h*)&mh0[ec * 16 + 4 * lg];
            bf1[ec] = *(const v4h*)&mh1[ec * 16 + 4 * lg];
        }
    }
    __syncthreads();

    float ls0 = 0.f, ls1 = 0.f;
    const float* nbase = nodes + (size_t)b * NN * 128;
    const float* mk0 = mask + (size_t)(b * PP + p0 + lp) * NN;
    const float* mk1 = mk0 + (size_t)16 * NN;

    // ping-pong register buffers; prefetch step s+1 while computing step s
    float4 nbA[8], nbB[8];
    k5_pref(0, wid, lp, lg, nbase, nbA);
    for (int s2 = 0; s2 < 4; s2++) {
        const int s = 2 * s2;
        k5_pref(s + 1, wid, lp, lg, nbase, nbB);
        k5_comp(s, wid, lp, lg, bf0, bf1, nbA, mk0, mk1, ls0, ls1, probs);
        if (s2 < 3) k5_pref(s + 2, wid, lp, lg, nbase, nbA);
        k5_comp(s + 1, wid, lp, lg, bf0, bf1, nbB, mk0, mk1, ls0, ls1, probs);
    }

    ls0 += __shfl_xor(ls0, 16);
    ls0 += __shfl_xor(ls0, 32);
    ls1 += __shfl_xor(ls1, 16);
    ls1 += __shfl_xor(ls1, 32);
    if (lane < 16) {
        atomicAdd(&rowsum[lane], ls0);
        atomicAdd(&rowsum[16 + lane], ls1);
    }
    __syncthreads();
    if (tid < 32) rowinv[tid] = 1.f / rowsum[tid];
    __syncthreads();

    if (tid < 500) {
        const int rg = tid / 250;             // 0..1: row-group of 16
        const int c4 = (tid - rg * 250) * 4;  // 0..996
        const size_t obase = (size_t)(b * PP + p0 + rg * 16) * NN;
#pragma unroll 4
        for (int r = 0; r < 16; r++) {
            v4h pv = *(const v4h*)&probs[(rg * 16 + r) * 1028 + c4];
            float inv = rowinv[rg * 16 + r];
            float4 ov;
            ov.x = (float)pv[0] * inv;
            ov.y = (float)pv[1] * inv;
            ov.z = (float)pv[2] * inv;
            ov.w = (float)pv[3] * inv;
            *(float4*)&out[obase + (size_t)r * NN + c4] = ov;
        }
    }
}

extern "C" void kernel_launch(void* const* d_in, const int* in_sizes, int n_in,
                              void* d_out, int out_size, void* d_ws, size_t ws_size,
                              hipStream_t stream) {
    const float* nodes = (const float*)d_in[0];
    const float* ln    = (const float*)d_in[1];
    const float* attr  = (const float*)d_in[2];
    const float* mask  = (const float*)d_in[3];
    const float* Wq    = (const float*)d_in[4];
    const float* Wk    = (const float*)d_in[5];
    const float* Wv    = (const float*)d_in[6];
    const float* Wo    = (const float*)d_in[7];
    const float* bo    = (const float*)d_in[8];
    float* out = (float*)d_out;

    // workspace layout (halfs): Aout fp16, Qh, Mh  (12.6 MB total)
    __fp16* AoutH = (__fp16*)d_ws;                     // 2,097,152 halfs
    __fp16* Qh    = AoutH + 2097152;                   // 2,097,152 halfs
    __fp16* Mhh   = Qh + 2097152;                      // 2,097,152 halfs

    // d_out doubles as fp16 K/V scratch (fully rewritten by k5 every launch)
    __fp16* Kf = (__fp16*)d_out;
    __fp16* Vt = Kf + (size_t)BB * HH * NP * 16;

    hipLaunchKernelGGL(k1_qproj, dim3(256), dim3(256), 0, stream, ln, attr, Wq, Qh);
    hipLaunchKernelGGL(k2_kv, dim3(16, 64, 2), dim3(256), 0, stream, nodes, Wk, Wv, Kf, Vt);
    hipLaunchKernelGGL(k3_attn, dim3(1024), dim3(256), 0, stream, Qh, Kf, Vt, mask, AoutH);
    hipLaunchKernelGGL(k4_mh, dim3(256), dim3(256), 0, stream, AoutH, Wo, bo, Mhh);
    hipLaunchKernelGGL(k5_final, dim3(512), dim3(512), 0, stream, nodes, Mhh, mask, out);
}

// Round 11
// 278.545 us; speedup vs baseline: 1.0697x; 1.0697x over previous
//
#include <hip/hip_runtime.h>

#define BB 64
#define PP 256
#define NN 1000
#define NP 1024   // padded KV rows (power of 2, zero-filled beyond NN)
#define EE 128
#define HH 8
#define DD 16
// H*D = 128

typedef __fp16 v4h __attribute__((ext_vector_type(4)));
typedef float v4f __attribute__((ext_vector_type(4)));

// Shared MFMA GEMM convention (validated in k3/k5 since R2):
//   af = X[m = lane&15][k = 4*(lane>>4)+j]      (v4h)
//   bf = W^T[n = lane&15][k = 4*(lane>>4)+j]    (v4h, from LDS)
//   D  = mfma(af, bf, acc):  acc[r] = C[m = 4*(lane>>4)+r][n = lane&15]

// ---------------------------------------------------------------------------
// k1: Q projection, MFMA.  Qh = 0.25 * (concat(ln, attr) @ Wq), fp16 out.
// ---------------------------------------------------------------------------
__global__ __launch_bounds__(256) void k1_qproj(const float* __restrict__ ln,
                                                const float* __restrict__ attr,
                                                const float* __restrict__ Wq,
                                                __fp16* __restrict__ Qh) {
    __shared__ __fp16 wt[128 * 132];   // Wq^T[n][k], first 128 k-rows
    __shared__ float attrs[64];
    const int tid = threadIdx.x;
    const int row0 = blockIdx.x * 64;   // 256 blocks
    for (int i = tid; i < 128 * 128; i += 256) {
        int k = i >> 7, n = i & 127;
        wt[n * 132 + k] = (__fp16)Wq[i];
    }
    if (tid < 64) attrs[tid] = attr[row0 + tid];
    __syncthreads();

    const int wid = tid >> 6, lane = tid & 63;
    const int lp = lane & 15, lg = lane >> 4;
    const int rb = row0 + wid * 16;

    const float* arow = ln + (size_t)(rb + lp) * 128;
    v4f acc[8];
#pragma unroll
    for (int cf = 0; cf < 8; cf++) acc[cf] = (v4f){0.f, 0.f, 0.f, 0.f};

#pragma unroll
    for (int k0 = 0; k0 < 8; k0++) {
        float4 av = *(const float4*)&arow[k0 * 16 + 4 * lg];
        v4h af;
        af[0] = (__fp16)av.x; af[1] = (__fp16)av.y;
        af[2] = (__fp16)av.z; af[3] = (__fp16)av.w;
#pragma unroll
        for (int cf = 0; cf < 8; cf++) {
            v4h bf = *(const v4h*)&wt[(cf * 16 + lp) * 132 + k0 * 16 + 4 * lg];
            acc[cf] = __builtin_amdgcn_mfma_f32_16x16x16f16(af, bf, acc[cf], 0, 0, 0);
        }
    }

#pragma unroll
    for (int cf = 0; cf < 8; cf++) {
        const int col = cf * 16 + lp;
        const float w128 = Wq[128 * 128 + col];
#pragma unroll
        for (int r = 0; r < 4; r++) {
            const int rl = wid * 16 + 4 * lg + r;
            float v = (acc[cf][r] + attrs[rl] * w128) * 0.25f;
            Qh[(size_t)(row0 + rl) * 128 + col] = (__fp16)v;
        }
    }
}

// ---------------------------------------------------------------------------
// k2: K/V projection, MFMA.  blockIdx.z: 0 -> Kf, 1 -> Vt.  Both stored as
// 16x16 tiles with ROTATED granule order so k3's LDS fragment reads are
// lane-linear (conflict-free):
//   Kf tile: half = (d>>2)*64 + n*4 + (d&3)
//   Vt tile: half = (n>>2)*64 + d*4 + (n&3)
// ---------------------------------------------------------------------------
__global__ __launch_bounds__(256) void k2_kv(const float* __restrict__ nodes,
                                             const float* __restrict__ Wk,
                                             const float* __restrict__ Wv,
                                             __fp16* __restrict__ Kf,
                                             __fp16* __restrict__ Vt) {
    __shared__ __fp16 wt[128 * 132];   // W^T[n][k]
    const int tid = threadIdx.x;
    const int b = blockIdx.y;
    const int kv = blockIdx.z;
    const float* W = (kv == 0) ? Wk : Wv;
    for (int i = tid; i < 128 * 128; i += 256) {
        int k = i >> 7, n = i & 127;
        wt[n * 132 + k] = (__fp16)W[i];
    }
    __syncthreads();

    const int wid = tid >> 6, lane = tid & 63;
    const int lp = lane & 15, lg = lane >> 4;
    const int nb = blockIdx.x * 64 + wid * 16;   // 16 x-blocks -> rows 0..1023

    int nr = nb + lp;
    if (nr >= NN) nr = NN - 1;                   // clamp; garbage zeroed on store
    const float* arow = nodes + (size_t)(b * NN + nr) * 128;

    v4f acc[8];
#pragma unroll
    for (int cf = 0; cf < 8; cf++) acc[cf] = (v4f){0.f, 0.f, 0.f, 0.f};

#pragma unroll
    for (int k0 = 0; k0 < 8; k0++) {
        float4 av = *(const float4*)&arow[k0 * 16 + 4 * lg];
        v4h af;
        af[0] = (__fp16)av.x; af[1] = (__fp16)av.y;
        af[2] = (__fp16)av.z; af[3] = (__fp16)av.w;
#pragma unroll
        for (int cf = 0; cf < 8; cf++) {
            v4h bf = *(const v4h*)&wt[(cf * 16 + lp) * 132 + k0 * 16 + 4 * lg];
            acc[cf] = __builtin_amdgcn_mfma_f32_16x16x16f16(af, bf, acc[cf], 0, 0, 0);
        }
    }

    if (kv == 0) {
        // element (n = nb+4lg+r, d = lp) -> half:
        //   (nb>>4)*256 + (lp>>2)*64 + (4lg+r)*4 + (lp&3)
#pragma unroll
        for (int cf = 0; cf < 8; cf++) {
            const size_t base = ((size_t)(b * HH + cf) << 14) +
                                (size_t)(nb >> 4) * 256 + (lp >> 2) * 64 + (lp & 3);
#pragma unroll
            for (int r = 0; r < 4; r++) {
                const int n = nb + 4 * lg + r;
                Kf[base + (4 * lg + r) * 4] = (n < NN) ? (__fp16)acc[cf][r] : (__fp16)0.f;
            }
        }
    } else {
        // v4h (n-quad lg, d = lp) -> half base: (nb>>4)*256 + lg*64 + lp*4
#pragma unroll
        for (int cf = 0; cf < 8; cf++) {
            v4h pk;
#pragma unroll
            for (int r = 0; r < 4; r++) {
                const int n = nb + 4 * lg + r;
                pk[r] = (n < NN) ? (__fp16)acc[cf][r] : (__fp16)0.f;
            }
            *(v4h*)&Vt[((size_t)(b * HH + cf) << 14) + (size_t)(nb >> 4) * 256 +
                       lg * 64 + lp * 4] = pk;
        }
    }
}

// ---------------------------------------------------------------------------
// k3: MFMA attention.  R15: R13's LDS-shared staging (request-rate optimal,
// conflict-free rotated layout) with tile-GROUPS of 4 per barrier interval:
// 16 barriers/block instead of 63.  All reg arrays statically indexed
// (#pragma unroll), v4h only, VGPR capped at 128 via launch_bounds.
// Numerics bit-identical to R13 (same per-tile body, same tile order).
// ---------------------------------------------------------------------------
__global__ __launch_bounds__(256, 4) void k3_attn(const __fp16* __restrict__ Qh,
                                                  const __fp16* __restrict__ Kf,
                                                  const __fp16* __restrict__ Vt,
                                                  const float* __restrict__ mask,
                                                  __fp16* __restrict__ Aout) {
    __shared__ __fp16 sh[2][4][1024];  // [buf][chunk: Kh0,Kh1,Vh0,Vh1][4 tiles]
    const int tid = threadIdx.x;
    const int bid = blockIdx.x;            // 1024
    const int b = bid & 63;                // bid&7 = b&7 -> XCD locality on b
    const int rest = bid >> 6;             // 0..15
    const int hg = rest & 3, pt = rest >> 2;
    const int h0 = hg * 2;
    const int p0 = pt * 64;

    const int wid = tid >> 6, lane = tid & 63;
    const int lp = lane & 15, lg = lane >> 4;
    const int pw = p0 + wid * 16;

    // staging source: wave w handles chunk w; tile t = halfs [t*256, t*256+256)
    const __fp16* gsrc = ((wid < 2) ? Kf + ((size_t)(b * HH + h0 + wid) << 14)
                                    : Vt + ((size_t)(b * HH + h0 + wid - 2) << 14)) +
                         lane * 4;

    v4h qf[2];
    {
        const __fp16* qrow = Qh + (size_t)(b * PP + pw + lp) * 128 + h0 * 16 + 4 * lg;
        qf[0] = *(const v4h*)&qrow[0];
        qf[1] = *(const v4h*)&qrow[16];
    }

    const float* mrow = mask + (size_t)(b * PP + pw + lp) * NN;
    const int foff = 64 * lg + 4 * lp;     // rotated-layout fragment offset (= lane*4)

    v4f acc[2];
    float lsum[2];
    acc[0] = (v4f){0.f, 0.f, 0.f, 0.f};
    acc[1] = (v4f){0.f, 0.f, 0.f, 0.f};
    lsum[0] = 0.f; lsum[1] = 0.f;
    const v4f zero4 = {0.f, 0.f, 0.f, 0.f};

    v4h stg[4], stgN[4];
    float4 mvc[4], mvn[4];

    // prologue: group 0 -> sh[0]; group 1 -> stg; mask group 0 -> mvc
    {
        v4h t0[4];
#pragma unroll
        for (int i = 0; i < 4; i++) t0[i] = *(const v4h*)(gsrc + i * 256);
#pragma unroll
        for (int i = 0; i < 4; i++) *(v4h*)&sh[0][wid][i * 256 + lane * 4] = t0[i];
#pragma unroll
        for (int i = 0; i < 4; i++) stg[i] = *(const v4h*)(gsrc + 1024 + i * 256);
#pragma unroll
        for (int i = 0; i < 4; i++)
            mvc[i] = *(const float4*)&mrow[i * 16 + 4 * lg];
    }
    __syncthreads();

    // invariants at top of superstep S: sh[S&1] = group S (tiles 4S..4S+3);
    // stg = group S+1; mvc = mask(group S).
    for (int S = 0; S < 15; S++) {
        const int p = S & 1;
        if (S < 14) {
#pragma unroll
            for (int i = 0; i < 4; i++)
                stgN[i] = *(const v4h*)(gsrc + (S + 2) * 1024 + i * 256);
        }
#pragma unroll
        for (int i = 0; i < 4; i++) {
            int moff = ((S + 1) * 4 + i) * 16 + 4 * lg;
            if (moff > 996) moff = 996;
            mvn[i] = *(const float4*)&mrow[moff];
        }

        // compute tiles 4S+i from sh[p]
#pragma unroll
        for (int i = 0; i < 4; i++) {
            const int off = i * 256 + foff;
            v4h kf0 = *(const v4h*)&sh[p][0][off];
            v4h kf1 = *(const v4h*)&sh[p][1][off];
            v4h vf0 = *(const v4h*)&sh[p][2][off];
            v4h vf1 = *(const v4h*)&sh[p][3][off];
            const float4 m = mvc[i];
            {
                v4f sc = __builtin_amdgcn_mfma_f32_16x16x16f16(kf0, qf[0], zero4, 0, 0, 0);
                float w0 = __expf(sc[0] + m.x);
                float w1 = __expf(sc[1] + m.y);
                float w2 = __expf(sc[2] + m.z);
                float w3 = __expf(sc[3] + m.w);
                lsum[0] += (w0 + w1) + (w2 + w3);
                v4h wf;
                wf[0] = (__fp16)w0; wf[1] = (__fp16)w1; wf[2] = (__fp16)w2; wf[3] = (__fp16)w3;
                acc[0] = __builtin_amdgcn_mfma_f32_16x16x16f16(wf, vf0, acc[0], 0, 0, 0);
            }
            {
                v4f sc = __builtin_amdgcn_mfma_f32_16x16x16f16(kf1, qf[1], zero4, 0, 0, 0);
                float w0 = __expf(sc[0] + m.x);
                float w1 = __expf(sc[1] + m.y);
                float w2 = __expf(sc[2] + m.z);
                float w3 = __expf(sc[3] + m.w);
                lsum[1] += (w0 + w1) + (w2 + w3);
                v4h wf;
                wf[0] = (__fp16)w0; wf[1] = (__fp16)w1; wf[2] = (__fp16)w2; wf[3] = (__fp16)w3;
                acc[1] = __builtin_amdgcn_mfma_f32_16x16x16f16(wf, vf1, acc[1], 0, 0, 0);
            }
        }

        // publish group S+1 into the other buffer (its last readers synced
        // at the barrier ending superstep S-1)
#pragma unroll
        for (int i = 0; i < 4; i++)
            *(v4h*)&sh[p ^ 1][wid][i * 256 + lane * 4] = stg[i];
        __syncthreads();

#pragma unroll
        for (int i = 0; i < 4; i++) { stg[i] = stgN[i]; mvc[i] = mvn[i]; }
    }

    // tail: group 15 in sh[1] — tiles 60,61 full; 62 guarded; 63 skipped
    {
#pragma unroll
        for (int i = 0; i < 2; i++) {
            const int off = i * 256 + foff;
            v4h kf0 = *(const v4h*)&sh[1][0][off];
            v4h kf1 = *(const v4h*)&sh[1][1][off];
            v4h vf0 = *(const v4h*)&sh[1][2][off];
            v4h vf1 = *(const v4h*)&sh[1][3][off];
            const float4 m = mvc[i];
            {
                v4f sc = __builtin_amdgcn_mfma_f32_16x16x16f16(kf0, qf[0], zero4, 0, 0, 0);
                float w0 = __expf(sc[0] + m.x);
                float w1 = __expf(sc[1] + m.y);
                float w2 = __expf(sc[2] + m.z);
                float w3 = __expf(sc[3] + m.w);
                lsum[0] += (w0 + w1) + (w2 + w3);
                v4h wf;
                wf[0] = (__fp16)w0; wf[1] = (__fp16)w1; wf[2] = (__fp16)w2; wf[3] = (__fp16)w3;
                acc[0] = __builtin_amdgcn_mfma_f32_16x16x16f16(wf, vf0, acc[0], 0, 0, 0);
            }
            {
                v4f sc = __builtin_amdgcn_mfma_f32_16x16x16f16(kf1, qf[1], zero4, 0, 0, 0);
                float w0 = __expf(sc[0] + m.x);
                float w1 = __expf(sc[1] + m.y);
                float w2 = __expf(sc[2] + m.z);
                float w3 = __expf(sc[3] + m.w);
                lsum[1] += (w0 + w1) + (w2 + w3);
                v4h wf;
                wf[0] = (__fp16)w0; wf[1] = (__fp16)w1; wf[2] = (__fp16)w2; wf[3] = (__fp16)w3;
                acc[1] = __builtin_amdgcn_mfma_f32_16x16x16f16(wf, vf1, acc[1], 0, 0, 0);
            }
        }
        {   // tile 62: n = 992 + 4*lg + r, bounds-guarded
            const int off = 2 * 256 + foff;
            const float4 m = mvc[2];
            const bool c0 = (992 + 4 * lg + 0 < NN), c1 = (992 + 4 * lg + 1 < NN);
            const bool c2 = (992 + 4 * lg + 2 < NN), c3 = (992 + 4 * lg + 3 < NN);
            v4h kf0 = *(const v4h*)&sh[1][0][off];
            v4h kf1 = *(const v4h*)&sh[1][1][off];
            v4h vf0 = *(const v4h*)&sh[1][2][off];
            v4h vf1 = *(const v4h*)&sh[1][3][off];
            {
                v4f sc = __builtin_amdgcn_mfma_f32_16x16x16f16(kf0, qf[0], zero4, 0, 0, 0);
                float w0 = c0 ? __expf(sc[0] + m.x) : 0.f;
                float w1 = c1 ? __expf(sc[1] + m.y) : 0.f;
                float w2 = c2 ? __expf(sc[2] + m.z) : 0.f;
                float w3 = c3 ? __expf(sc[3] + m.w) : 0.f;
                lsum[0] += (w0 + w1) + (w2 + w3);
                v4h wf;
                wf[0] = (__fp16)w0; wf[1] = (__fp16)w1; wf[2] = (__fp16)w2; wf[3] = (__fp16)w3;
                acc[0] = __builtin_amdgcn_mfma_f32_16x16x16f16(wf, vf0, acc[0], 0, 0, 0);
            }
            {
                v4f sc = __builtin_amdgcn_mfma_f32_16x16x16f16(kf1, qf[1], zero4, 0, 0, 0);
                float w0 = c0 ? __expf(sc[0] + m.x) : 0.f;
                float w1 = c1 ? __expf(sc[1] + m.y) : 0.f;
                float w2 = c2 ? __expf(sc[2] + m.z) : 0.f;
                float w3 = c3 ? __expf(sc[3] + m.w) : 0.f;
                lsum[1] += (w0 + w1) + (w2 + w3);
                v4h wf;
                wf[0] = (__fp16)w0; wf[1] = (__fp16)w1; wf[2] = (__fp16)w2; wf[3] = (__fp16)w3;
                acc[1] = __builtin_amdgcn_mfma_f32_16x16x16f16(wf, vf1, acc[1], 0, 0, 0);
            }
        }
    }

#pragma unroll
    for (int j = 0; j < 2; j++) {
        float l = lsum[j];
        l += __shfl_xor(l, 16);
        l += __shfl_xor(l, 32);
#pragma unroll
        for (int r = 0; r < 4; r++) {
            float denom = __shfl(l, 4 * lg + r);
            float inv = 1.f / denom;
            Aout[(size_t)(b * PP + pw + 4 * lg + r) * 128 + (h0 + j) * 16 + lp] =
                (__fp16)(acc[j][r] * inv);
        }
    }
}

// ---------------------------------------------------------------------------
// k4: mh MFMA.  Ain fp16 (values identical — fp16 rounding moved to k3 store).
// ---------------------------------------------------------------------------
__global__ __launch_bounds__(256) void k4_mh(const __fp16* __restrict__ Ain,
                                             const float* __restrict__ Wo,
                                             const float* __restrict__ bo,
                                             __fp16* __restrict__ Mh) {
    __shared__ __fp16 wt[128 * 132];   // Wo^T[n][k]
    const int tid = threadIdx.x;
    const int row0 = blockIdx.x * 64;
    for (int i = tid; i < 128 * 128; i += 256) {
        int k = i >> 7, n = i & 127;
        wt[n * 132 + k] = (__fp16)Wo[i];
    }
    __syncthreads();

    const int wid = tid >> 6, lane = tid & 63;
    const int lp = lane & 15, lg = lane >> 4;
    const int rb = row0 + wid * 16;

    const __fp16* arow = Ain + (size_t)(rb + lp) * 128;
    v4f acc[8];
#pragma unroll
    for (int cf = 0; cf < 8; cf++) acc[cf] = (v4f){0.f, 0.f, 0.f, 0.f};

#pragma unroll
    for (int k0 = 0; k0 < 8; k0++) {
        v4h af = *(const v4h*)&arow[k0 * 16 + 4 * lg];
#pragma unroll
        for (int cf = 0; cf < 8; cf++) {
            v4h bf = *(const v4h*)&wt[(cf * 16 + lp) * 132 + k0 * 16 + 4 * lg];
            acc[cf] = __builtin_amdgcn_mfma_f32_16x16x16f16(af, bf, acc[cf], 0, 0, 0);
        }
    }

    const float scale = 0.08838834764831845f;   // 1/sqrt(128)
#pragma unroll
    for (int cf = 0; cf < 8; cf++) {
        const int col = cf * 16 + lp;
        const float bb = bo[col];
#pragma unroll
        for (int r = 0; r < 4; r++) {
            const int rl = wid * 16 + 4 * lg + r;
            Mh[(size_t)(row0 + rl) * 128 + col] = (__fp16)((acc[cf][r] + bb) * scale);
        }
    }
}

// ---------------------------------------------------------------------------
// k5: final scoring + tanh-clip softmax.  R11 structure (512 threads,
// 32 p-rows/block, nodes reuse x2, fp32 register double-buffer).
// ---------------------------------------------------------------------------
__device__ __forceinline__ void k5_pref(int s, int wid, int lp, int lg,
                                        const float* __restrict__ nbase,
                                        float4 (&nb)[8]) {
    int nr = s * 128 + wid * 16 + lp;
    if (nr >= NN) nr = NN - 1;
    const float* a = nbase + (size_t)nr * 128 + 4 * lg;
#pragma unroll
    for (int ec = 0; ec < 8; ec++) nb[ec] = *(const float4*)&a[ec * 16];
}

__device__ __forceinline__ void k5_comp(int s, int wid, int lp, int lg,
                                        const v4h (&bf0)[8], const v4h (&bf1)[8],
                                        const float4 (&nb)[8],
                                        const float* __restrict__ mk0,
                                        const float* __restrict__ mk1,
                                        float& ls0, float& ls1,
                                        __fp16* __restrict__ probs) {
    const v4f zero4 = {0.f, 0.f, 0.f, 0.f};
    int mc = s * 128 + wid * 16 + 4 * lg;
    if (mc > 996) mc = 996;
    float4 m0 = *(const float4*)&mk0[mc];
    float4 m1 = *(const float4*)&mk1[mc];
    v4f a0 = zero4, a1 = zero4;
#pragma unroll
    for (int ec = 0; ec < 8; ec++) {
        float4 av = nb[ec];
        v4h af;
        af[0] = (__fp16)av.x; af[1] = (__fp16)av.y;
        af[2] = (__fp16)av.z; af[3] = (__fp16)av.w;
        a0 = __builtin_amdgcn_mfma_f32_16x16x16f16(af, bf0[ec], a0, 0, 0, 0);
        a1 = __builtin_amdgcn_mfma_f32_16x16x16f16(af, bf1[ec], a1, 0, 0, 0);
    }
    const int nt = s * 128 + wid * 16;
    const int nb4 = nt + 4 * lg;
#pragma unroll
    for (int t = 0; t < 2; t++) {
        const v4f ac = t ? a1 : a0;
        const float4 m = t ? m1 : m0;
        v4h wf;
        float ws = 0.f;
        if (nt + 15 < NN) {
            float e0 = __expf(2.f * ac[0]);
            float e1 = __expf(2.f * ac[1]);
            float e2 = __expf(2.f * ac[2]);
            float e3 = __expf(2.f * ac[3]);
            float w0 = __expf(fmaf(-20.f, __builtin_amdgcn_rcpf(e0 + 1.f), m.x));
            float w1 = __expf(fmaf(-20.f, __builtin_amdgcn_rcpf(e1 + 1.f), m.y));
            float w2 = __expf(fmaf(-20.f, __builtin_amdgcn_rcpf(e2 + 1.f), m.z));
            float w3 = __expf(fmaf(-20.f, __builtin_amdgcn_rcpf(e3 + 1.f), m.w));
            ws = (w0 + w1) + (w2 + w3);
            wf[0] = (__fp16)w0; wf[1] = (__fp16)w1; wf[2] = (__fp16)w2; wf[3] = (__fp16)w3;
        } else {
            float w0 = 0.f, w1 = 0.f, w2 = 0.f, w3 = 0.f;
            if (nb4 + 0 < NN) {
                float e = __expf(2.f * ac[0]);
                w0 = __expf(fmaf(-20.f, __builtin_amdgcn_rcpf(e + 1.f), m.x));
            }
            if (nb4 + 1 < NN) {
                float e = __expf(2.f * ac[1]);
                w1 = __expf(fmaf(-20.f, __builtin_amdgcn_rcpf(e + 1.f), m.y));
            }
            if (nb4 + 2 < NN) {
                float e = __expf(2.f * ac[2]);
                w2 = __expf(fmaf(-20.f, __builtin_amdgcn_rcpf(e + 1.f), m.z));
            }
            if (nb4 + 3 < NN) {
                float e = __expf(2.f * ac[3]);
                w3 = __expf(fmaf(-20.f, __builtin_amdgcn_rcpf(e + 1.f), m.w));
            }
            ws = (w0 + w1) + (w2 + w3);
            wf[0] = (__fp16)w0; wf[1] = (__fp16)w1; wf[2] = (__fp16)w2; wf[3] = (__fp16)w3;
        }
        if (t) ls1 += ws; else ls0 += ws;
        *(v4h*)&probs[(t * 16 + lp) * 1028 + nb4] = wf;
    }
}

__global__ __launch_bounds__(512, 4) void k5_final(const float* __restrict__ nodes,
                                                   const __fp16* __restrict__ Mh,
                                                   const float* __restrict__ mask,
                                                   float* __restrict__ out) {
    __shared__ __fp16 probs[32 * 1028];   // 65,792 B
    __shared__ float rowsum[32];
    __shared__ float rowinv[32];
    const int tid = threadIdx.x;
    const int bid = blockIdx.x;          // 512 = 64 b x 8 pt; b&7 = bid&7 (XCD)
    const int xcd = bid & 7;
    const int pt = (bid >> 3) & 7;
    const int b = ((bid >> 6) << 3) | xcd;
    const int p0 = pt * 32;

    if (tid < 32) rowsum[tid] = 0.f;

    const int wid = tid >> 6, lane = tid & 63;
    const int lp = lane & 15, lg = lane >> 4;

    v4h bf0[8], bf1[8];
    {
        const __fp16* mh0 = Mh + (size_t)(b * PP + p0 + lp) * 128;
        const __fp16* mh1 = mh0 + (size_t)16 * 128;
#pragma unroll
        for (int ec = 0; ec < 8; ec++) {
            bf0[ec] = *(const v4h*)&mh0[ec * 16 + 4 * lg];
            bf1[ec] = *(const v4h*)&mh1[ec * 16 + 4 * lg];
        }
    }
    __syncthreads();

    float ls0 = 0.f, ls1 = 0.f;
    const float* nbase = nodes + (size_t)b * NN * 128;
    const float* mk0 = mask + (size_t)(b * PP + p0 + lp) * NN;
    const float* mk1 = mk0 + (size_t)16 * NN;

    // ping-pong register buffers; prefetch step s+1 while computing step s
    float4 nbA[8], nbB[8];
    k5_pref(0, wid, lp, lg, nbase, nbA);
    for (int s2 = 0; s2 < 4; s2++) {
        const int s = 2 * s2;
        k5_pref(s + 1, wid, lp, lg, nbase, nbB);
        k5_comp(s, wid, lp, lg, bf0, bf1, nbA, mk0, mk1, ls0, ls1, probs);
        if (s2 < 3) k5_pref(s + 2, wid, lp, lg, nbase, nbA);
        k5_comp(s + 1, wid, lp, lg, bf0, bf1, nbB, mk0, mk1, ls0, ls1, probs);
    }

    ls0 += __shfl_xor(ls0, 16);
    ls0 += __shfl_xor(ls0, 32);
    ls1 += __shfl_xor(ls1, 16);
    ls1 += __shfl_xor(ls1, 32);
    if (lane < 16) {
        atomicAdd(&rowsum[lane], ls0);
        atomicAdd(&rowsum[16 + lane], ls1);
    }
    __syncthreads();
    if (tid < 32) rowinv[tid] = 1.f / rowsum[tid];
    __syncthreads();

    if (tid < 500) {
        const int rg = tid / 250;             // 0..1: row-group of 16
        const int c4 = (tid - rg * 250) * 4;  // 0..996
        const size_t obase = (size_t)(b * PP + p0 + rg * 16) * NN;
#pragma unroll 4
        for (int r = 0; r < 16; r++) {
            v4h pv = *(const v4h*)&probs[(rg * 16 + r) * 1028 + c4];
            float inv = rowinv[rg * 16 + r];
            float4 ov;
            ov.x = (float)pv[0] * inv;
            ov.y = (float)pv[1] * inv;
            ov.z = (float)pv[2] * inv;
            ov.w = (float)pv[3] * inv;
            *(float4*)&out[obase + (size_t)r * NN + c4] = ov;
        }
    }
}

extern "C" void kernel_launch(void* const* d_in, const int* in_sizes, int n_in,
                              void* d_out, int out_size, void* d_ws, size_t ws_size,
                              hipStream_t stream) {
    const float* nodes = (const float*)d_in[0];
    const float* ln    = (const float*)d_in[1];
    const float* attr  = (const float*)d_in[2];
    const float* mask  = (const float*)d_in[3];
    const float* Wq    = (const float*)d_in[4];
    const float* Wk    = (const float*)d_in[5];
    const float* Wv    = (const float*)d_in[6];
    const float* Wo    = (const float*)d_in[7];
    const float* bo    = (const float*)d_in[8];
    float* out = (float*)d_out;

    // workspace layout (halfs): Aout fp16, Qh, Mh  (12.6 MB total)
    __fp16* AoutH = (__fp16*)d_ws;                     // 2,097,152 halfs
    __fp16* Qh    = AoutH + 2097152;                   // 2,097,152 halfs
    __fp16* Mhh   = Qh + 2097152;                      // 2,097,152 halfs

    // d_out doubles as fp16 K/V scratch (fully rewritten by k5 every launch)
    __fp16* Kf = (__fp16*)d_out;
    __fp16* Vt = Kf + (size_t)BB * HH * NP * 16;

    hipLaunchKernelGGL(k1_qproj, dim3(256), dim3(256), 0, stream, ln, attr, Wq, Qh);
    hipLaunchKernelGGL(k2_kv, dim3(16, 64, 2), dim3(256), 0, stream, nodes, Wk, Wv, Kf, Vt);
    hipLaunchKernelGGL(k3_attn, dim3(1024), dim3(256), 0, stream, Qh, Kf, Vt, mask, AoutH);
    hipLaunchKernelGGL(k4_mh, dim3(256), dim3(256), 0, stream, AoutH, Wo, bo, Mhh);
    hipLaunchKernelGGL(k5_final, dim3(512), dim3(512), 0, stream, nodes, Mhh, mask, out);
}